// Round 1
// baseline (237.692 us; speedup 1.0000x reference)
//
#include <hip/hip_runtime.h>

#define GROUP 8
#define BS 4096
#define CH 512

typedef __attribute__((ext_vector_type(4))) float f32x4;
typedef __attribute__((ext_vector_type(8))) short bf16x8;
typedef __attribute__((ext_vector_type(8))) unsigned short u16x8;

static __device__ __forceinline__ unsigned short f2bf(float f) {
    unsigned int u = __builtin_bit_cast(unsigned int, f);
    u += 0x7FFFu + ((u >> 16) & 1u);   // round-to-nearest-even
    return (unsigned short)(u >> 16);
}

// ---------------------------------------------------------------------------
// Kernel 1: transpose weight  wt[g][i][c] = w[g][c][i]  (so v_i is contiguous)
// ---------------------------------------------------------------------------
__global__ __launch_bounds__(256) void k_transpose(const float* __restrict__ w,
                                                   float* __restrict__ wt) {
    __shared__ float tile[64][65];
    int b = blockIdx.x;
    int g = b >> 6;              // 64 tiles per group
    int tt = b & 63;
    int i0 = (tt & 7) * 64;
    int c0 = (tt >> 3) * 64;
    const float* wg = w + (size_t)g * CH * CH;
    float* wtg = wt + (size_t)g * CH * CH;
    int col = threadIdx.x & 63;
    int r4  = threadIdx.x >> 6;  // 0..3
#pragma unroll
    for (int it = 0; it < 16; ++it) {
        int r = it * 4 + r4;
        tile[r][col] = wg[(size_t)(c0 + r) * CH + i0 + col];
    }
    __syncthreads();
#pragma unroll
    for (int it = 0; it < 16; ++it) {
        int r = it * 4 + r4;
        wtg[(size_t)(i0 + r) * CH + c0 + col] = tile[col][r];
    }
}

// ---------------------------------------------------------------------------
// Kernel 2: inv_denom[g][i] = 2 / sum_c v_i[c]^2   (one wave per (g,i))
// ---------------------------------------------------------------------------
__global__ __launch_bounds__(256) void k_denom(const float* __restrict__ wt,
                                               float* __restrict__ invd) {
    int wid  = (blockIdx.x * 256 + threadIdx.x) >> 6;  // 0..4095
    int lane = threadIdx.x & 63;
    const float4* vp = (const float4*)(wt + (size_t)wid * CH) + lane * 2;
    float4 a = vp[0], b = vp[1];
    float s = a.x*a.x + a.y*a.y + a.z*a.z + a.w*a.w
            + b.x*b.x + b.y*b.y + b.z*b.z + b.w*b.w;
#pragma unroll
    for (int off = 32; off; off >>= 1) s += __shfl_xor(s, off, 64);
    if (lane == 0) invd[wid] = 2.0f / s;
}

// ---------------------------------------------------------------------------
// Kernel 3: build Q = H_0 H_1 ... H_511 per group, by evolving identity rows.
// One wave per Q-row; row (512 fp32) lives in 8 VGPRs/lane.
// ---------------------------------------------------------------------------
__global__ __launch_bounds__(256) void k_qbuild(const float* __restrict__ wt,
                                                const float* __restrict__ invd,
                                                float* __restrict__ Q) {
    int wid  = (blockIdx.x * 256 + threadIdx.x) >> 6;  // 0..4095 (= g*512 + r)
    int g    = wid >> 9;
    int r    = wid & 511;
    int lane = threadIdx.x & 63;

    float q[8];
#pragma unroll
    for (int j = 0; j < 8; ++j) q[j] = (lane * 8 + j == r) ? 1.0f : 0.0f;

    const float* wtg = wt + (size_t)g * CH * CH;
    const float* idg = invd + g * CH;

    for (int i = 0; i < CH; ++i) {
        const float4* vp = (const float4*)(wtg + (size_t)i * CH) + lane * 2;
        float4 va = vp[0], vb = vp[1];
        float v[8] = {va.x, va.y, va.z, va.w, vb.x, vb.y, vb.z, vb.w};
        float dot = 0.f;
#pragma unroll
        for (int j = 0; j < 8; ++j) dot += q[j] * v[j];
#pragma unroll
        for (int off = 32; off; off >>= 1) dot += __shfl_xor(dot, off, 64);
        float s = dot * idg[i];
#pragma unroll
        for (int j = 0; j < 8; ++j) q[j] -= s * v[j];
    }

    float4* qp = (float4*)(Q + (size_t)wid * CH) + lane * 2;
    qp[0] = make_float4(q[0], q[1], q[2], q[3]);
    qp[1] = make_float4(q[4], q[5], q[6], q[7]);
}

// ---------------------------------------------------------------------------
// Kernel 4: out[g] = x[g] (4096x512) @ Q[g] (512x512), bf16 MFMA, fp32 acc.
// 128x128 tile, BK=32, 4 waves (2x2), each wave 64x64 = 4x4 fragments.
// ---------------------------------------------------------------------------
#define BM 128
#define BN 128
#define BK 32
#define LDP 40   // padded LDS row length (ushorts): 32 + 8 (16B pad)

__global__ __launch_bounds__(256) void k_gemm(const float* __restrict__ x,
                                              const float* __restrict__ Q,
                                              float* __restrict__ out) {
    __shared__ unsigned short Al[BM * LDP];
    __shared__ unsigned short Bl[BN * LDP];

    int bid = blockIdx.x;
    int g  = bid >> 7;          // 128 blocks per group
    int tn = (bid >> 5) & 3;    // col tile (consecutive bids share B -> L2)
    int tm = bid & 31;          // row tile

    int t    = threadIdx.x;
    int lane = t & 63;
    int w    = t >> 6;
    int wr   = w >> 1, wc = w & 1;

    const float* xg = x + (size_t)g * BS * CH + (size_t)tm * BM * CH;
    const float* Qg = Q + (size_t)g * CH * CH + (size_t)tn * BN;
    float* og = out + (size_t)g * BS * CH + (size_t)tm * BM * CH + (size_t)tn * BN;

    f32x4 acc[4][4];
#pragma unroll
    for (int mi = 0; mi < 4; ++mi)
#pragma unroll
        for (int ni = 0; ni < 4; ++ni)
#pragma unroll
            for (int z = 0; z < 4; ++z) acc[mi][ni][z] = 0.f;

    int a_k4 = t & 7;      // float4 index within BK
    int a_r  = t >> 3;     // 0..31
    int b_n  = t & 127;    // n within tile
    int b_kh = t >> 7;     // 0..1  (k-half)

    int fr = lane & 15, kg = lane >> 4;

    for (int ks = 0; ks < CH / BK; ++ks) {
        int k0 = ks * BK;
        __syncthreads();
        // ---- stage A: x tile (128 x 32) fp32 -> bf16, row-major padded ----
#pragma unroll
        for (int rr = 0; rr < 4; ++rr) {
            int r = a_r + 32 * rr;
            float4 v = *(const float4*)(xg + (size_t)r * CH + k0 + a_k4 * 4);
            ushort4 h;
            h.x = f2bf(v.x); h.y = f2bf(v.y); h.z = f2bf(v.z); h.w = f2bf(v.w);
            *(ushort4*)(&Al[r * LDP + a_k4 * 4]) = h;
        }
        // ---- stage B transposed: Bl[n][k] = Q[k0+kk][tn*128+n] -> bf16 ----
        {
            u16x8 lo, hi;
#pragma unroll
            for (int j = 0; j < 8; ++j)
                lo[j] = f2bf(Qg[(size_t)(k0 + b_kh * 16 + j) * CH + b_n]);
#pragma unroll
            for (int j = 0; j < 8; ++j)
                hi[j] = f2bf(Qg[(size_t)(k0 + b_kh * 16 + 8 + j) * CH + b_n]);
            *(u16x8*)(&Bl[b_n * LDP + b_kh * 16]) = lo;
            *(u16x8*)(&Bl[b_n * LDP + b_kh * 16 + 8]) = hi;
        }
        __syncthreads();
        // ---- fragments + MFMA ----
        bf16x8 af[4], bf[4];
#pragma unroll
        for (int mi = 0; mi < 4; ++mi)
            af[mi] = *(const bf16x8*)(&Al[(wr * 64 + mi * 16 + fr) * LDP + kg * 8]);
#pragma unroll
        for (int ni = 0; ni < 4; ++ni)
            bf[ni] = *(const bf16x8*)(&Bl[(wc * 64 + ni * 16 + fr) * LDP + kg * 8]);
#pragma unroll
        for (int mi = 0; mi < 4; ++mi)
#pragma unroll
            for (int ni = 0; ni < 4; ++ni)
                acc[mi][ni] = __builtin_amdgcn_mfma_f32_16x16x32_bf16(
                    af[mi], bf[ni], acc[mi][ni], 0, 0, 0);
    }

    // ---- epilogue: D[row=(l>>4)*4+rj][col=l&15] ----
    int rg = lane >> 4;
#pragma unroll
    for (int mi = 0; mi < 4; ++mi)
#pragma unroll
        for (int ni = 0; ni < 4; ++ni)
#pragma unroll
            for (int rj = 0; rj < 4; ++rj) {
                int grow = wr * 64 + mi * 16 + rg * 4 + rj;
                int gcol = wc * 64 + ni * 16 + fr;
                og[(size_t)grow * CH + gcol] = acc[mi][ni][rj];
            }
}

// ---------------------------------------------------------------------------
extern "C" void kernel_launch(void* const* d_in, const int* in_sizes, int n_in,
                              void* d_out, int out_size, void* d_ws, size_t ws_size,
                              hipStream_t stream) {
    const float* x = (const float*)d_in[0];   // (8, 4096, 512)
    const float* w = (const float*)d_in[1];   // (8, 512, 512)
    float* out = (float*)d_out;

    // d_out doubles as scratch for wt/invd (dead before k_gemm overwrites it).
    float* wt   = out;                 // 8*512*512 fp32 = 8 MB
    float* invd = out + 2097152;       // 4096 fp32
    float* Q    = (float*)d_ws;        // 8*512*512 fp32 = 8 MB

    hipLaunchKernelGGL(k_transpose, dim3(512),  dim3(256), 0, stream, w, wt);
    hipLaunchKernelGGL(k_denom,     dim3(1024), dim3(256), 0, stream, wt, invd);
    hipLaunchKernelGGL(k_qbuild,    dim3(1024), dim3(256), 0, stream, wt, invd, Q);
    hipLaunchKernelGGL(k_gemm,      dim3(1024), dim3(256), 0, stream, x, Q, out);
}

// Round 2
// 197.613 us; speedup vs baseline: 1.2028x; 1.2028x over previous
//
#include <hip/hip_runtime.h>

#define GROUP 8
#define BS 4096
#define CH 512

typedef __attribute__((ext_vector_type(4))) float f32x4;
typedef __attribute__((ext_vector_type(8))) short bf16x8;
typedef __attribute__((ext_vector_type(8))) unsigned short u16x8;

static __device__ __forceinline__ unsigned short f2bf(float f) {
    unsigned int u = __builtin_bit_cast(unsigned int, f);
    u += 0x7FFFu + ((u >> 16) & 1u);   // round-to-nearest-even
    return (unsigned short)(u >> 16);
}

// Full wave64 sum via DPP (row_shr 1/2/4/8, bcast15, bcast31), total in lane 63,
// returned as wave-uniform scalar via readlane.
static __device__ __forceinline__ float wave_sum64(float s) {
    int x;
#define DPP_STEP(ctrl)                                                         \
    x = __builtin_amdgcn_update_dpp(0, __builtin_bit_cast(int, s), ctrl, 0xf,  \
                                    0xf, true);                                \
    s += __builtin_bit_cast(float, x);
    DPP_STEP(0x111)  // row_shr:1
    DPP_STEP(0x112)  // row_shr:2
    DPP_STEP(0x114)  // row_shr:4
    DPP_STEP(0x118)  // row_shr:8
    DPP_STEP(0x142)  // row_bcast:15
    DPP_STEP(0x143)  // row_bcast:31
#undef DPP_STEP
    return __builtin_bit_cast(float,
        __builtin_amdgcn_readlane(__builtin_bit_cast(int, s), 63));
}

// ---------------------------------------------------------------------------
// Kernel 1: transpose weight  wt[g][i][c] = w[g][c][i]  (so v_i is contiguous)
// ---------------------------------------------------------------------------
__global__ __launch_bounds__(256) void k_transpose(const float* __restrict__ w,
                                                   float* __restrict__ wt) {
    __shared__ float tile[64][65];
    int b = blockIdx.x;
    int g = b >> 6;
    int tt = b & 63;
    int i0 = (tt & 7) * 64;
    int c0 = (tt >> 3) * 64;
    const float* wg = w + (size_t)g * CH * CH;
    float* wtg = wt + (size_t)g * CH * CH;
    int col = threadIdx.x & 63;
    int r4  = threadIdx.x >> 6;
#pragma unroll
    for (int it = 0; it < 16; ++it) {
        int r = it * 4 + r4;
        tile[r][col] = wg[(size_t)(c0 + r) * CH + i0 + col];
    }
    __syncthreads();
#pragma unroll
    for (int it = 0; it < 16; ++it) {
        int r = it * 4 + r4;
        wtg[(size_t)(i0 + r) * CH + c0 + col] = tile[col][r];
    }
}

// ---------------------------------------------------------------------------
// Kernel 2: inv_denom[g][i] = 2 / sum_c v_i[c]^2   (one wave per (g,i))
// ---------------------------------------------------------------------------
__global__ __launch_bounds__(256) void k_denom(const float* __restrict__ wt,
                                               float* __restrict__ invd) {
    int wid  = (blockIdx.x * 256 + threadIdx.x) >> 6;
    int lane = threadIdx.x & 63;
    const float4* vp = (const float4*)(wt + (size_t)wid * CH) + lane * 2;
    float4 a = vp[0], b = vp[1];
    float s = a.x*a.x + a.y*a.y + a.z*a.z + a.w*a.w
            + b.x*b.x + b.y*b.y + b.z*b.z + b.w*b.w;
    float tot = wave_sum64(s);
    if (lane == 0) invd[wid] = 2.0f / tot;
}

// ---------------------------------------------------------------------------
// Kernel 3: build Q = H_0 H_1 ... H_511 per group by evolving identity rows.
// 256 blocks x 512 threads (8 waves). Each block: one group, 16 rows.
// Each wave: 2 rows. v-chunks (8 reflections = 16 KB) double-buffered in LDS,
// shared by all 8 waves -> L2 traffic 512 MB (was 4.3 GB).
// Lane owns cols {4*lane..4*lane+3, 256+4*lane..+3} (stride-16B, conflict-free).
// ---------------------------------------------------------------------------
#define CHUNK 8
#define NCHUNK (CH / CHUNK)

__global__ __launch_bounds__(512, 2) void k_qbuild(const float* __restrict__ wt,
                                                   const float* __restrict__ invd,
                                                   float* __restrict__ Q) {
    __shared__ float vbuf[2][CHUNK * CH];

    int t    = threadIdx.x;
    int lane = t & 63;
    int w    = t >> 6;              // wave 0..7
    int bid  = blockIdx.x;          // 0..255
    int g    = bid >> 5;            // 32 blocks per group
    int rb   = bid & 31;            // row-block within group (16 rows each)
    int r0   = rb * 16 + w * 2;     // this wave's first row
    int r1   = r0 + 1;

    const float* wtg = wt + (size_t)g * CH * CH;
    const float* idg = invd + g * CH;

    // q registers: cols j<4 -> 4*lane+j ; j>=4 -> 256+4*lane+(j-4)
    float q0[8], q1[8];
#pragma unroll
    for (int j = 0; j < 8; ++j) {
        int col = (j < 4) ? (4 * lane + j) : (256 + 4 * lane + j - 4);
        q0[j] = (col == r0) ? 1.0f : 0.0f;
        q1[j] = (col == r1) ? 1.0f : 0.0f;
    }

    // prologue: stage chunk 0
    {
        const float* src = wtg;
        float* dst = vbuf[0];
        *(float4*)(dst + 4 * t)        = *(const float4*)(src + 4 * t);
        *(float4*)(dst + 2048 + 4 * t) = *(const float4*)(src + 2048 + 4 * t);
    }

    for (int c = 0; c < NCHUNK; ++c) {
        __syncthreads();
        if (c + 1 < NCHUNK) {
            const float* src = wtg + (size_t)(c + 1) * CHUNK * CH;
            float* dst = vbuf[(c + 1) & 1];
            *(float4*)(dst + 4 * t)        = *(const float4*)(src + 4 * t);
            *(float4*)(dst + 2048 + 4 * t) = *(const float4*)(src + 2048 + 4 * t);
        }
        const float* buf = vbuf[c & 1];
        float bb[CHUNK];
#pragma unroll
        for (int j = 0; j < CHUNK; ++j) bb[j] = idg[c * CHUNK + j];

#pragma unroll
        for (int j = 0; j < CHUNK; ++j) {
            const float* vb = buf + j * CH;
            float4 va = *(const float4*)(vb + 4 * lane);
            float4 vc = *(const float4*)(vb + 256 + 4 * lane);
            float v[8] = {va.x, va.y, va.z, va.w, vc.x, vc.y, vc.z, vc.w};
            float d0 = 0.f, d1 = 0.f;
#pragma unroll
            for (int k = 0; k < 8; ++k) { d0 += q0[k] * v[k]; d1 += q1[k] * v[k]; }
            float s0 = wave_sum64(d0) * bb[j];
            float s1 = wave_sum64(d1) * bb[j];
#pragma unroll
            for (int k = 0; k < 8; ++k) { q0[k] -= s0 * v[k]; q1[k] -= s1 * v[k]; }
        }
    }

    float* qr0 = Q + (size_t)(g * CH + r0) * CH;
    float* qr1 = Q + (size_t)(g * CH + r1) * CH;
    *(float4*)(qr0 + 4 * lane)       = make_float4(q0[0], q0[1], q0[2], q0[3]);
    *(float4*)(qr0 + 256 + 4 * lane) = make_float4(q0[4], q0[5], q0[6], q0[7]);
    *(float4*)(qr1 + 4 * lane)       = make_float4(q1[0], q1[1], q1[2], q1[3]);
    *(float4*)(qr1 + 256 + 4 * lane) = make_float4(q1[4], q1[5], q1[6], q1[7]);
}

// ---------------------------------------------------------------------------
// Kernel 4: out[g] = x[g] (4096x512) @ Q[g] (512x512), bf16 MFMA, fp32 acc.
// 128x128 tile, BK=32, 4 waves (2x2), each wave 64x64 = 4x4 fragments.
// ---------------------------------------------------------------------------
#define BM 128
#define BN 128
#define BK 32
#define LDP 40   // padded LDS row length (ushorts): 32 + 8 (16B pad)

__global__ __launch_bounds__(256) void k_gemm(const float* __restrict__ x,
                                              const float* __restrict__ Q,
                                              float* __restrict__ out) {
    __shared__ unsigned short Al[BM * LDP];
    __shared__ unsigned short Bl[BN * LDP];

    int bid = blockIdx.x;
    int g  = bid >> 7;
    int tn = (bid >> 5) & 3;
    int tm = bid & 31;

    int t    = threadIdx.x;
    int lane = t & 63;
    int w    = t >> 6;
    int wr   = w >> 1, wc = w & 1;

    const float* xg = x + (size_t)g * BS * CH + (size_t)tm * BM * CH;
    const float* Qg = Q + (size_t)g * CH * CH + (size_t)tn * BN;
    float* og = out + (size_t)g * BS * CH + (size_t)tm * BM * CH + (size_t)tn * BN;

    f32x4 acc[4][4];
#pragma unroll
    for (int mi = 0; mi < 4; ++mi)
#pragma unroll
        for (int ni = 0; ni < 4; ++ni)
#pragma unroll
            for (int z = 0; z < 4; ++z) acc[mi][ni][z] = 0.f;

    int a_k4 = t & 7;
    int a_r  = t >> 3;
    int b_n  = t & 127;
    int b_kh = t >> 7;

    int fr = lane & 15, kg = lane >> 4;

    for (int ks = 0; ks < CH / BK; ++ks) {
        int k0 = ks * BK;
        __syncthreads();
#pragma unroll
        for (int rr = 0; rr < 4; ++rr) {
            int r = a_r + 32 * rr;
            float4 v = *(const float4*)(xg + (size_t)r * CH + k0 + a_k4 * 4);
            ushort4 h;
            h.x = f2bf(v.x); h.y = f2bf(v.y); h.z = f2bf(v.z); h.w = f2bf(v.w);
            *(ushort4*)(&Al[r * LDP + a_k4 * 4]) = h;
        }
        {
            u16x8 lo, hi;
#pragma unroll
            for (int j = 0; j < 8; ++j)
                lo[j] = f2bf(Qg[(size_t)(k0 + b_kh * 16 + j) * CH + b_n]);
#pragma unroll
            for (int j = 0; j < 8; ++j)
                hi[j] = f2bf(Qg[(size_t)(k0 + b_kh * 16 + 8 + j) * CH + b_n]);
            *(u16x8*)(&Bl[b_n * LDP + b_kh * 16]) = lo;
            *(u16x8*)(&Bl[b_n * LDP + b_kh * 16 + 8]) = hi;
        }
        __syncthreads();
        bf16x8 af[4], bfr[4];
#pragma unroll
        for (int mi = 0; mi < 4; ++mi)
            af[mi] = *(const bf16x8*)(&Al[(wr * 64 + mi * 16 + fr) * LDP + kg * 8]);
#pragma unroll
        for (int ni = 0; ni < 4; ++ni)
            bfr[ni] = *(const bf16x8*)(&Bl[(wc * 64 + ni * 16 + fr) * LDP + kg * 8]);
#pragma unroll
        for (int mi = 0; mi < 4; ++mi)
#pragma unroll
            for (int ni = 0; ni < 4; ++ni)
                acc[mi][ni] = __builtin_amdgcn_mfma_f32_16x16x32_bf16(
                    af[mi], bfr[ni], acc[mi][ni], 0, 0, 0);
    }

    int rg = lane >> 4;
#pragma unroll
    for (int mi = 0; mi < 4; ++mi)
#pragma unroll
        for (int ni = 0; ni < 4; ++ni)
#pragma unroll
            for (int rj = 0; rj < 4; ++rj) {
                int grow = wr * 64 + mi * 16 + rg * 4 + rj;
                int gcol = wc * 64 + ni * 16 + fr;
                og[(size_t)grow * CH + gcol] = acc[mi][ni][rj];
            }
}

// ---------------------------------------------------------------------------
extern "C" void kernel_launch(void* const* d_in, const int* in_sizes, int n_in,
                              void* d_out, int out_size, void* d_ws, size_t ws_size,
                              hipStream_t stream) {
    const float* x = (const float*)d_in[0];   // (8, 4096, 512)
    const float* w = (const float*)d_in[1];   // (8, 512, 512)
    float* out = (float*)d_out;

    // d_out doubles as scratch for wt/invd (dead before k_gemm overwrites it).
    float* wt   = out;                 // 8*512*512 fp32 = 8 MB
    float* invd = out + 2097152;       // 4096 fp32
    float* Q    = (float*)d_ws;        // 8*512*512 fp32 = 8 MB

    hipLaunchKernelGGL(k_transpose, dim3(512),  dim3(256), 0, stream, w, wt);
    hipLaunchKernelGGL(k_denom,     dim3(1024), dim3(256), 0, stream, wt, invd);
    hipLaunchKernelGGL(k_qbuild,    dim3(256),  dim3(512), 0, stream, wt, invd, Q);
    hipLaunchKernelGGL(k_gemm,      dim3(1024), dim3(256), 0, stream, x, Q, out);
}

// Round 3
// 196.838 us; speedup vs baseline: 1.2075x; 1.0039x over previous
//
#include <hip/hip_runtime.h>

#define GROUP 8
#define BS 4096
#define CH 512
#define PW 32        // panel width (reflections per panel)
#define NPANEL 16    // CH / PW

typedef __attribute__((ext_vector_type(4))) float f32x4;
typedef __attribute__((ext_vector_type(8))) short bf16x8;

static __device__ __forceinline__ unsigned short f2bf(float f) {
    unsigned int u = __builtin_bit_cast(unsigned int, f);
    u += 0x7FFFu + ((u >> 16) & 1u);   // round-to-nearest-even
    return (unsigned short)(u >> 16);
}
static __device__ __forceinline__ float bf2f(unsigned short h) {
    return __builtin_bit_cast(float, (unsigned int)h << 16);
}
// split fp32[8] -> bf16 hi + bf16 lo (hi+lo captures ~16 mantissa bits)
static __device__ __forceinline__ void split8(const float* v, bf16x8& h, bf16x8& l) {
#pragma unroll
    for (int j = 0; j < 8; ++j) {
        unsigned short hu = f2bf(v[j]);
        h[j] = (short)hu;
        l[j] = (short)f2bf(v[j] - bf2f(hu));
    }
}

// ---------------------------------------------------------------------------
// Kernel 1: transpose weight  wt[g][i][c] = w[g][c][i]  (v_i contiguous rows)
// ---------------------------------------------------------------------------
__global__ __launch_bounds__(256) void k_transpose(const float* __restrict__ w,
                                                   float* __restrict__ wt) {
    __shared__ float tile[64][65];
    int b = blockIdx.x;
    int g = b >> 6;
    int tt = b & 63;
    int i0 = (tt & 7) * 64;
    int c0 = (tt >> 3) * 64;
    const float* wg = w + (size_t)g * CH * CH;
    float* wtg = wt + (size_t)g * CH * CH;
    int col = threadIdx.x & 63;
    int r4  = threadIdx.x >> 6;
#pragma unroll
    for (int it = 0; it < 16; ++it) {
        int r = it * 4 + r4;
        tile[r][col] = wg[(size_t)(c0 + r) * CH + i0 + col];
    }
    __syncthreads();
#pragma unroll
    for (int it = 0; it < 16; ++it) {
        int r = it * 4 + r4;
        wtg[(size_t)(i0 + r) * CH + c0 + col] = tile[col][r];
    }
}

// ---------------------------------------------------------------------------
// Kernel 2: per-panel prep. For panel p of group g (128 blocks, 256 thr):
//   S = Y Y^T (32x32, split-bf16 MFMA, K=512)      [beta_i = 2/S_ii]
//   T: upper-tri recurrence T[i][k] = -beta_k * sum_{j=i..k-1} T[i][j] S[j][k]
//   M^T = (T Y^T)^T = Yt * T^T  (512x32, split-bf16 MFMA, K=32)
// Outputs: Yh/Yl [g][512 rows][512] bf16;  Mth/Mtl [g][p][c=512][i=32] bf16.
// ---------------------------------------------------------------------------
__global__ __launch_bounds__(256) void k_panelprep(const float* __restrict__ wt,
                                                   unsigned short* __restrict__ Yh,
                                                   unsigned short* __restrict__ Yl,
                                                   unsigned short* __restrict__ Mth,
                                                   unsigned short* __restrict__ Mtl) {
    __shared__ float Ylds[PW][516];   // 66 KB, stride 516 w -> 2-way banks
    __shared__ float Sp[4][PW][36];   // per-wave partial S
    __shared__ float S_ls[PW][36];
    __shared__ float T_ls[PW][36];
    __shared__ float betaL[PW];

    int t    = threadIdx.x;
    int lane = t & 63;
    int w    = t >> 6;           // wave 0..3
    int fr   = lane & 15;
    int kg   = lane >> 4;        // 0..3
    int g    = blockIdx.x >> 4;
    int p    = blockIdx.x & 15;

    const float* Ysrc = wt + ((size_t)g * CH + p * PW) * CH;

    // stage Y panel rows (32 x 512 fp32)
    for (int idx4 = t; idx4 < PW * 128; idx4 += 256) {
        int r = idx4 >> 7, c4 = idx4 & 127;
        *(float4*)&Ylds[r][c4 * 4] = *(const float4*)(Ysrc + (size_t)r * CH + c4 * 4);
    }
    __syncthreads();

    // ---- S = Y Y^T via split MFMA; wave w covers kk = 4w..4w+3 ----
    {
        f32x4 sacc[2][2];
#pragma unroll
        for (int a = 0; a < 2; ++a)
#pragma unroll
            for (int b = 0; b < 2; ++b)
#pragma unroll
                for (int z = 0; z < 4; ++z) sacc[a][b][z] = 0.f;
#pragma unroll
        for (int kki = 0; kki < 4; ++kki) {
            int kk = 4 * w + kki;
            bf16x8 fh[2], fl[2];
#pragma unroll
            for (int h = 0; h < 2; ++h) {
                float a8[8];
                const float* src = &Ylds[h * 16 + fr][kk * 32 + kg * 8];
#pragma unroll
                for (int j = 0; j < 8; ++j) a8[j] = src[j];
                split8(a8, fh[h], fl[h]);
            }
#pragma unroll
            for (int a = 0; a < 2; ++a)
#pragma unroll
                for (int b = 0; b < 2; ++b) {
                    sacc[a][b] = __builtin_amdgcn_mfma_f32_16x16x32_bf16(fh[a], fh[b], sacc[a][b], 0, 0, 0);
                    sacc[a][b] = __builtin_amdgcn_mfma_f32_16x16x32_bf16(fh[a], fl[b], sacc[a][b], 0, 0, 0);
                    sacc[a][b] = __builtin_amdgcn_mfma_f32_16x16x32_bf16(fl[a], fh[b], sacc[a][b], 0, 0, 0);
                }
        }
#pragma unroll
        for (int a = 0; a < 2; ++a)
#pragma unroll
            for (int b = 0; b < 2; ++b)
#pragma unroll
                for (int j = 0; j < 4; ++j)
                    Sp[w][a * 16 + kg * 4 + j][b * 16 + fr] = sacc[a][b][j];
    }
    __syncthreads();
    for (int idx = t; idx < PW * PW; idx += 256) {
        int r = idx >> 5, c = idx & 31;
        S_ls[r][c] = Sp[0][r][c] + Sp[1][r][c] + Sp[2][r][c] + Sp[3][r][c];
    }
    __syncthreads();
    if (t < PW) betaL[t] = 2.0f / S_ls[t][t];
    for (int idx = t; idx < PW * 36; idx += 256) ((float*)T_ls)[idx] = 0.f;
    __syncthreads();
    if (t < PW) T_ls[t][t] = betaL[t];
    __syncthreads();
    // ---- T recurrence (32 sequential steps, rows parallel across threads) ----
    for (int k = 1; k < PW; ++k) {
        if (t < k) {
            float acc = 0.f;
            for (int j = t; j < k; ++j) acc += T_ls[t][j] * S_ls[j][k];
            T_ls[t][k] = -betaL[k] * acc;
        }
        __syncthreads();
    }

    // ---- M^T = Yt * T^T (512x32, K=32): wave w covers rf = 8w..8w+7 ----
    bf16x8 tbh[2], tbl[2];
#pragma unroll
    for (int cf = 0; cf < 2; ++cf) {
        float t8[8];
        const float* src = &T_ls[cf * 16 + fr][kg * 8];
#pragma unroll
        for (int j = 0; j < 8; ++j) t8[j] = src[j];
        split8(t8, tbh[cf], tbl[cf]);
    }
#pragma unroll
    for (int rfi = 0; rfi < 8; ++rfi) {
        int rf = 8 * w + rfi;
        float a8[8];
#pragma unroll
        for (int j = 0; j < 8; ++j) a8[j] = Ylds[kg * 8 + j][rf * 16 + fr];  // Y^T column-read
        bf16x8 ah, al;
        split8(a8, ah, al);
#pragma unroll
        for (int cf = 0; cf < 2; ++cf) {
            f32x4 m;
#pragma unroll
            for (int z = 0; z < 4; ++z) m[z] = 0.f;
            m = __builtin_amdgcn_mfma_f32_16x16x32_bf16(ah, tbh[cf], m, 0, 0, 0);
            m = __builtin_amdgcn_mfma_f32_16x16x32_bf16(ah, tbl[cf], m, 0, 0, 0);
            m = __builtin_amdgcn_mfma_f32_16x16x32_bf16(al, tbh[cf], m, 0, 0, 0);
#pragma unroll
            for (int j = 0; j < 4; ++j) {
                int c = rf * 16 + kg * 4 + j;
                int i = cf * 16 + fr;
                size_t off = (((size_t)(g * NPANEL + p) * CH) + c) * PW + i;
                unsigned short hu = f2bf(m[j]);
                Mth[off] = hu;
                Mtl[off] = f2bf(m[j] - bf2f(hu));
            }
        }
    }

    // ---- export Y panel as bf16 hi/lo (row-major [g][512][512]) ----
    for (int idx = t; idx < PW * CH; idx += 256) {
        int r = idx >> 9, c = idx & 511;
        float v = Ylds[r][c];
        size_t off = ((size_t)g * CH + p * PW + r) * CH + c;
        unsigned short hu = f2bf(v);
        Yh[off] = hu;
        Yl[off] = f2bf(v - bf2f(hu));
    }
}

// ---------------------------------------------------------------------------
// Kernel 3: build Q via 16 sequential rank-32 panel updates (MFMA, hi/lo split).
// 256 blocks x 256 thr (4 waves); block owns 16 Q-rows (fp32 in LDS).
// Per panel: D = Q*Y_p^T (16x32, K=512; waves K-split via Dbuf), then
//            Q -= D*M_p (16x512, K=32; waves split col-frags).
// Y/Mt fragments read directly from global (L2-resident, full-line patterns).
// ---------------------------------------------------------------------------
__global__ __launch_bounds__(256) void k_qpanels(const unsigned short* __restrict__ Yh,
                                                 const unsigned short* __restrict__ Yl,
                                                 const unsigned short* __restrict__ Mth,
                                                 const unsigned short* __restrict__ Mtl,
                                                 float* __restrict__ Q) {
    __shared__ float Qlds[16][516];    // 33 KB
    __shared__ float Dbuf[4][16][36];  // per-wave partial D

    int t    = threadIdx.x;
    int lane = t & 63;
    int w    = t >> 6;
    int fr   = lane & 15;
    int kg   = lane >> 4;
    int g    = blockIdx.x >> 5;
    int rb   = blockIdx.x & 31;
    int r0   = rb * 16;

    // Q = identity rows r0..r0+15
    for (int idx = t; idx < 16 * 516; idx += 256) ((float*)Qlds)[idx] = 0.f;
    __syncthreads();
    if (t < 16) Qlds[t][r0 + t] = 1.0f;
    __syncthreads();

    const unsigned short* Yh_g = Yh + (size_t)g * CH * CH;
    const unsigned short* Yl_g = Yl + (size_t)g * CH * CH;
    const unsigned short* Mth_g = Mth + (size_t)g * NPANEL * CH * PW;
    const unsigned short* Mtl_g = Mtl + (size_t)g * NPANEL * CH * PW;

    for (int p = 0; p < NPANEL; ++p) {
        // ---- D-GEMM: wave w accumulates kk = 4w..4w+3 ----
        f32x4 dacc[2];
#pragma unroll
        for (int cf = 0; cf < 2; ++cf)
#pragma unroll
            for (int z = 0; z < 4; ++z) dacc[cf][z] = 0.f;
#pragma unroll
        for (int kki = 0; kki < 4; ++kki) {
            int kk = 4 * w + kki;
            float a8[8];
            const float* qsrc = &Qlds[fr][kk * 32 + kg * 8];
#pragma unroll
            for (int j = 0; j < 8; ++j) a8[j] = qsrc[j];
            bf16x8 ah, al;
            split8(a8, ah, al);
#pragma unroll
            for (int cf = 0; cf < 2; ++cf) {
                size_t yoff = ((size_t)(p * PW + cf * 16 + fr)) * CH + kk * 32 + kg * 8;
                bf16x8 bh = *(const bf16x8*)(Yh_g + yoff);
                bf16x8 bl = *(const bf16x8*)(Yl_g + yoff);
                dacc[cf] = __builtin_amdgcn_mfma_f32_16x16x32_bf16(ah, bh, dacc[cf], 0, 0, 0);
                dacc[cf] = __builtin_amdgcn_mfma_f32_16x16x32_bf16(ah, bl, dacc[cf], 0, 0, 0);
                dacc[cf] = __builtin_amdgcn_mfma_f32_16x16x32_bf16(al, bh, dacc[cf], 0, 0, 0);
            }
        }
#pragma unroll
        for (int cf = 0; cf < 2; ++cf)
#pragma unroll
            for (int j = 0; j < 4; ++j)
                Dbuf[w][kg * 4 + j][cf * 16 + fr] = dacc[cf][j];
        __syncthreads();

        // ---- sum K-partials, split D (A-frag: row=fr, k = kg*8+j over i=32) ----
        float dsum[8];
#pragma unroll
        for (int j = 0; j < 8; ++j)
            dsum[j] = Dbuf[0][fr][kg * 8 + j] + Dbuf[1][fr][kg * 8 + j] +
                      Dbuf[2][fr][kg * 8 + j] + Dbuf[3][fr][kg * 8 + j];
        bf16x8 dh, dl;
        split8(dsum, dh, dl);

        // ---- U-GEMM + Q RMW: wave w covers col-frags 8w..8w+7 ----
#pragma unroll
        for (int cfi = 0; cfi < 8; ++cfi) {
            int cf2 = w * 8 + cfi;
            size_t moff = ((size_t)p * CH + cf2 * 16 + fr) * PW + kg * 8;
            bf16x8 mh = *(const bf16x8*)(Mth_g + moff);
            bf16x8 ml = *(const bf16x8*)(Mtl_g + moff);
            f32x4 u;
#pragma unroll
            for (int z = 0; z < 4; ++z) u[z] = 0.f;
            u = __builtin_amdgcn_mfma_f32_16x16x32_bf16(dh, mh, u, 0, 0, 0);
            u = __builtin_amdgcn_mfma_f32_16x16x32_bf16(dh, ml, u, 0, 0, 0);
            u = __builtin_amdgcn_mfma_f32_16x16x32_bf16(dl, mh, u, 0, 0, 0);
#pragma unroll
            for (int j = 0; j < 4; ++j)
                Qlds[kg * 4 + j][cf2 * 16 + fr] -= u[j];
        }
        __syncthreads();
    }

    float* Qg = Q + ((size_t)g * CH + r0) * CH;
    for (int idx = t; idx < 16 * CH; idx += 256) {
        int r = idx >> 9, c = idx & 511;
        Qg[(size_t)r * CH + c] = Qlds[r][c];
    }
}

// ---------------------------------------------------------------------------
// Kernel 4: out[g] = x[g] (4096x512) @ Q[g] (512x512), bf16 MFMA, fp32 acc.
// ---------------------------------------------------------------------------
#define BM 128
#define BN 128
#define BK 32
#define LDP 40

__global__ __launch_bounds__(256) void k_gemm(const float* __restrict__ x,
                                              const float* __restrict__ Q,
                                              float* __restrict__ out) {
    __shared__ unsigned short Al[BM * LDP];
    __shared__ unsigned short Bl[BN * LDP];

    int bid = blockIdx.x;
    int g  = bid >> 7;
    int tn = (bid >> 5) & 3;
    int tm = bid & 31;

    int t    = threadIdx.x;
    int lane = t & 63;
    int w    = t >> 6;
    int wr   = w >> 1, wc = w & 1;

    const float* xg = x + (size_t)g * BS * CH + (size_t)tm * BM * CH;
    const float* Qg = Q + (size_t)g * CH * CH + (size_t)tn * BN;
    float* og = out + (size_t)g * BS * CH + (size_t)tm * BM * CH + (size_t)tn * BN;

    f32x4 acc[4][4];
#pragma unroll
    for (int mi = 0; mi < 4; ++mi)
#pragma unroll
        for (int ni = 0; ni < 4; ++ni)
#pragma unroll
            for (int z = 0; z < 4; ++z) acc[mi][ni][z] = 0.f;

    int a_k4 = t & 7;
    int a_r  = t >> 3;
    int b_n  = t & 127;
    int b_kh = t >> 7;

    int fr = lane & 15, kg = lane >> 4;

    typedef __attribute__((ext_vector_type(8))) unsigned short u16x8;
    for (int ks = 0; ks < CH / BK; ++ks) {
        int k0 = ks * BK;
        __syncthreads();
#pragma unroll
        for (int rr = 0; rr < 4; ++rr) {
            int r = a_r + 32 * rr;
            float4 v = *(const float4*)(xg + (size_t)r * CH + k0 + a_k4 * 4);
            ushort4 h;
            h.x = f2bf(v.x); h.y = f2bf(v.y); h.z = f2bf(v.z); h.w = f2bf(v.w);
            *(ushort4*)(&Al[r * LDP + a_k4 * 4]) = h;
        }
        {
            u16x8 lo, hi;
#pragma unroll
            for (int j = 0; j < 8; ++j)
                lo[j] = f2bf(Qg[(size_t)(k0 + b_kh * 16 + j) * CH + b_n]);
#pragma unroll
            for (int j = 0; j < 8; ++j)
                hi[j] = f2bf(Qg[(size_t)(k0 + b_kh * 16 + 8 + j) * CH + b_n]);
            *(u16x8*)(&Bl[b_n * LDP + b_kh * 16]) = lo;
            *(u16x8*)(&Bl[b_n * LDP + b_kh * 16 + 8]) = hi;
        }
        __syncthreads();
        bf16x8 af[4], bfr[4];
#pragma unroll
        for (int mi = 0; mi < 4; ++mi)
            af[mi] = *(const bf16x8*)(&Al[(wr * 64 + mi * 16 + fr) * LDP + kg * 8]);
#pragma unroll
        for (int ni = 0; ni < 4; ++ni)
            bfr[ni] = *(const bf16x8*)(&Bl[(wc * 64 + ni * 16 + fr) * LDP + kg * 8]);
#pragma unroll
        for (int mi = 0; mi < 4; ++mi)
#pragma unroll
            for (int ni = 0; ni < 4; ++ni)
                acc[mi][ni] = __builtin_amdgcn_mfma_f32_16x16x32_bf16(
                    af[mi], bfr[ni], acc[mi][ni], 0, 0, 0);
    }

    int rg = lane >> 4;
#pragma unroll
    for (int mi = 0; mi < 4; ++mi)
#pragma unroll
        for (int ni = 0; ni < 4; ++ni)
#pragma unroll
            for (int rj = 0; rj < 4; ++rj) {
                int grow = wr * 64 + mi * 16 + rg * 4 + rj;
                int gcol = wc * 64 + ni * 16 + fr;
                og[(size_t)grow * CH + gcol] = acc[mi][ni][rj];
            }
}

// ---------------------------------------------------------------------------
extern "C" void kernel_launch(void* const* d_in, const int* in_sizes, int n_in,
                              void* d_out, int out_size, void* d_ws, size_t ws_size,
                              hipStream_t stream) {
    const float* x = (const float*)d_in[0];   // (8, 4096, 512)
    const float* w = (const float*)d_in[1];   // (8, 512, 512)
    float* out = (float*)d_out;

    // scratch carved out of d_out (64 MB; all dead before k_gemm writes it):
    //   wt  [0,8MB)  Yh [8,12)  Yl [12,16)  Mth [16,20)  Mtl [20,24)
    char* ob = (char*)d_out;
    float*          wt  = (float*)ob;
    unsigned short* Yh  = (unsigned short*)(ob + (8u  << 20));
    unsigned short* Yl  = (unsigned short*)(ob + (12u << 20));
    unsigned short* Mth = (unsigned short*)(ob + (16u << 20));
    unsigned short* Mtl = (unsigned short*)(ob + (20u << 20));
    float* Q = (float*)d_ws;  // 8 MB

    hipLaunchKernelGGL(k_transpose, dim3(512),  dim3(256), 0, stream, w, wt);
    hipLaunchKernelGGL(k_panelprep, dim3(128),  dim3(256), 0, stream, wt, Yh, Yl, Mth, Mtl);
    hipLaunchKernelGGL(k_qpanels,   dim3(256),  dim3(256), 0, stream, Yh, Yl, Mth, Mtl, Q);
    hipLaunchKernelGGL(k_gemm,      dim3(1024), dim3(256), 0, stream, x, Q, out);
}